// Round 17
// baseline (5085.677 us; speedup 1.0000x reference)
//
#include <hip/hip_runtime.h>

#define FLT_MAX_C 3.402823466e+38f

typedef __attribute__((ext_vector_type(8))) __bf16 bf16x8;
typedef __attribute__((ext_vector_type(4))) float f32x4;

static __device__ __forceinline__ ushort f2bf(float x) {
    union { float f; unsigned u; } v; v.f = x;
    unsigned r = (v.u + 0x7FFFu + ((v.u >> 16) & 1u)) >> 16;
    return (ushort)r;
}

// bijective XCD swizzle (m204)
static __device__ __forceinline__ void xcd_swz(int& bx, int& by) {
    const int gx = gridDim.x;
    const int nwg = gx * gridDim.y;
    const int bid = blockIdx.y * gx + blockIdx.x;
    const int q = nwg >> 3, r = nwg & 7;
    const int xcd = bid & 7, lid = bid >> 3;
    const int swz = (xcd < r ? xcd * (q + 1) : r * (q + 1) + (xcd - r) * q) + lid;
    bx = swz % gx;
    by = swz / gx;
}

// ======== fp32 GEMM wide body: 128x256, 8x16 microtile, BK=8, LDS dbuf ===
// Pool layout: As[2][8][128] = 2x4096 B at offset 0; Bs[2][8][260] =
// 2x8320 B at offset 8192. TOTAL 24832 B (R16 undersized this -> OOB).
// One barrier per K-step: issue loads(t+1) -> compute(t, buf b) ->
// write buf b^1 -> barrier. k-ascending FMA order -> bitwise-identical z.
template<bool RELU>
__device__ __forceinline__ void gemm_f32_wide_dev(
    const float* __restrict__ A, const float* __restrict__ W,
    const float* __restrict__ bias, float* __restrict__ C, int K, int N,
    int bxi, int byi, void* smem)
{
    float (*As)[8][128] = (float(*)[8][128])smem;                    // 2x4096B
    float (*Bs)[8][260] = (float(*)[8][260])((char*)smem + 8192);    // 2x8320B
    const int tid = threadIdx.x;
    const int bm = byi << 7;
    const int bn = bxi << 8;

    const int la_row = tid >> 1;
    const int la_k   = (tid & 1) << 2;
    const int tm4 = (tid >> 4) << 2;
    const int tn4 = (tid & 15) << 2;
    const int bf_row  = tid >> 6;
    const int bf_col4 = (tid & 63) << 2;

    float acc[8][16];
    #pragma unroll
    for (int i = 0; i < 8; ++i)
        #pragma unroll
        for (int j = 0; j < 16; ++j) acc[i][j] = 0.f;

    const float* aptr = A + (size_t)(bm + la_row) * K + la_k;
    const float* bptr = W + (size_t)bf_row * N + bn + bf_col4;

    // preload + stage t=0 into buffer 0
    float4 av = *(const float4*)(aptr);
    float4 bv0 = *(const float4*)(bptr);
    float4 bv1 = *(const float4*)(bptr + (size_t)4 * N);
    As[0][la_k + 0][la_row] = av.x;
    As[0][la_k + 1][la_row] = av.y;
    As[0][la_k + 2][la_row] = av.z;
    As[0][la_k + 3][la_row] = av.w;
    *(float4*)(&Bs[0][bf_row][bf_col4])     = bv0;
    *(float4*)(&Bs[0][bf_row + 4][bf_col4]) = bv1;
    __syncthreads();

    const int nt = K >> 3;
    for (int t = 0; t < nt; ++t) {
        const int b = t & 1;
        if (t + 1 < nt) {                      // issue next loads early
            const int k0n = (t + 1) << 3;
            av  = *(const float4*)(aptr + k0n);
            bv0 = *(const float4*)(bptr + (size_t)k0n * N);
            bv1 = *(const float4*)(bptr + (size_t)(k0n + 4) * N);
        }
        #pragma unroll
        for (int kk = 0; kk < 8; ++kk) {       // compute overlaps VMEM
            float a[8], bfr[16];
            *(float4*)(a)      = *(const float4*)(&As[b][kk][tm4]);
            *(float4*)(a + 4)  = *(const float4*)(&As[b][kk][tm4 + 64]);
            #pragma unroll
            for (int q = 0; q < 4; ++q)
                *(float4*)(bfr + q * 4) = *(const float4*)(&Bs[b][kk][tn4 + 64 * q]);
            #pragma unroll
            for (int i = 0; i < 8; ++i)
                #pragma unroll
                for (int j = 0; j < 16; ++j)
                    acc[i][j] = fmaf(a[i], bfr[j], acc[i][j]);
        }
        if (t + 1 < nt) {                      // write-late into other buffer
            As[b ^ 1][la_k + 0][la_row] = av.x;
            As[b ^ 1][la_k + 1][la_row] = av.y;
            As[b ^ 1][la_k + 2][la_row] = av.z;
            As[b ^ 1][la_k + 3][la_row] = av.w;
            *(float4*)(&Bs[b ^ 1][bf_row][bf_col4])     = bv0;
            *(float4*)(&Bs[b ^ 1][bf_row + 4][bf_col4]) = bv1;
        }
        __syncthreads();                       // single barrier per step
    }

    float bb[16];
    #pragma unroll
    for (int q = 0; q < 4; ++q)
        #pragma unroll
        for (int jj = 0; jj < 4; ++jj)
            bb[q * 4 + jj] = bias[bn + tn4 + 64 * q + jj];

    #pragma unroll
    for (int i = 0; i < 8; ++i) {
        int row = bm + tm4 + (i < 4 ? i : 60 + i);
        float* cp = C + (size_t)row * N + bn + tn4;
        #pragma unroll
        for (int q = 0; q < 4; ++q) {
            float4 v;
            v.x = acc[i][q * 4 + 0] + bb[q * 4 + 0];
            v.y = acc[i][q * 4 + 1] + bb[q * 4 + 1];
            v.z = acc[i][q * 4 + 2] + bb[q * 4 + 2];
            v.w = acc[i][q * 4 + 3] + bb[q * 4 + 3];
            if (RELU) {
                v.x = fmaxf(v.x, 0.f); v.y = fmaxf(v.y, 0.f);
                v.z = fmaxf(v.z, 0.f); v.w = fmaxf(v.w, 0.f);
            }
            *(float4*)(cp + 64 * q) = v;
        }
    }
}

// ========== fp32 GEMM small-M body (BM=64, BN=128, BK=16) for enc4 ==========
template<bool RELU>
__device__ __forceinline__ void gemm_f32_64_dev(
    const float* __restrict__ A, const float* __restrict__ W,
    const float* __restrict__ bias, float* __restrict__ C, int K, int N,
    int bxi, int byi)
{
    __shared__ float As[16][64];
    __shared__ float Bs[16][132];
    const int tid = threadIdx.x;
    const int bm = byi << 6;
    const int bn = bxi << 7;

    const int la_row = tid & 63;
    const int la_k   = (tid >> 6) << 2;
    const int lb_row = tid >> 5;
    const int lb_col = (tid & 31) << 2;
    const int tr = tid >> 4;
    const int tc = tid & 15;

    float acc[4][8];
    #pragma unroll
    for (int i = 0; i < 4; ++i)
        #pragma unroll
        for (int j = 0; j < 8; ++j) acc[i][j] = 0.f;

    const float* aptr = A + (size_t)(bm + la_row) * K + la_k;
    const float* bptr = W + (size_t)lb_row * N + bn + lb_col;

    float4 av = *(const float4*)(aptr);
    float4 bv0 = *(const float4*)(bptr);
    float4 bv1 = *(const float4*)(bptr + (size_t)8 * N);

    for (int k0 = 0; k0 < K; k0 += 16) {
        __syncthreads();
        As[la_k + 0][la_row] = av.x;
        As[la_k + 1][la_row] = av.y;
        As[la_k + 2][la_row] = av.z;
        As[la_k + 3][la_row] = av.w;
        *(float4*)(&Bs[lb_row][lb_col]) = bv0;
        *(float4*)(&Bs[lb_row + 8][lb_col]) = bv1;
        __syncthreads();
        if (k0 + 16 < K) {
            av  = *(const float4*)(aptr + k0 + 16);
            bv0 = *(const float4*)(bptr + (size_t)(k0 + 16) * N);
            bv1 = *(const float4*)(bptr + (size_t)(k0 + 24) * N);
        }
        #pragma unroll
        for (int kk = 0; kk < 16; ++kk) {
            float a[4], b[8];
            *(float4*)(a) = *(const float4*)(&As[kk][tr << 2]);
            *(float4*)(b)     = *(const float4*)(&Bs[kk][tc << 2]);
            *(float4*)(b + 4) = *(const float4*)(&Bs[kk][(tc << 2) + 64]);
            #pragma unroll
            for (int i = 0; i < 4; ++i)
                #pragma unroll
                for (int j = 0; j < 8; ++j)
                    acc[i][j] = fmaf(a[i], b[j], acc[i][j]);
        }
    }

    float bb[8];
    #pragma unroll
    for (int j = 0; j < 8; ++j)
        bb[j] = bias[bn + (tc << 2) + (j < 4 ? j : 60 + j)];

    #pragma unroll
    for (int i = 0; i < 4; ++i) {
        float* cp = C + (size_t)(bm + (tr << 2) + i) * N + bn + (tc << 2);
        float4 v0, v1;
        v0.x = acc[i][0] + bb[0]; v0.y = acc[i][1] + bb[1];
        v0.z = acc[i][2] + bb[2]; v0.w = acc[i][3] + bb[3];
        v1.x = acc[i][4] + bb[4]; v1.y = acc[i][5] + bb[5];
        v1.z = acc[i][6] + bb[6]; v1.w = acc[i][7] + bb[7];
        if (RELU) {
            v0.x = fmaxf(v0.x, 0.f); v0.y = fmaxf(v0.y, 0.f);
            v0.z = fmaxf(v0.z, 0.f); v0.w = fmaxf(v0.w, 0.f);
            v1.x = fmaxf(v1.x, 0.f); v1.y = fmaxf(v1.y, 0.f);
            v1.w = fmaxf(v1.w, 0.f); v1.z = fmaxf(v1.z, 0.f);
        }
        *(float4*)(cp) = v0;
        *(float4*)(cp + 64) = v1;
    }
}

// ====== bf16 MFMA GEMM (decoder): K_STEP=32, 2-phase double-buffer ======
template<bool RELU, bool OUTF32>
__device__ __forceinline__ void gemm_bf16_dev(
    const ushort* __restrict__ A, const ushort* __restrict__ Wt,
    const float* __restrict__ bias, void* __restrict__ C, int K, int N,
    int bxi, int byi)
{
    __shared__ __align__(16) ushort As[2][128][32];
    __shared__ __align__(16) ushort Bs[2][128][32];
    const int tid  = threadIdx.x;
    const int lane = tid & 63;
    const int wv   = tid >> 6;
    const int wm   = (wv >> 1) << 6;
    const int wn   = (wv & 1) << 6;
    const int bm   = byi << 7;
    const int bn   = bxi << 7;
    const int lr   = lane & 15;
    const int lh   = lane >> 4;

    f32x4 acc[4][4];
    #pragma unroll
    for (int m = 0; m < 4; ++m)
        #pragma unroll
        for (int n = 0; n < 4; ++n) acc[m][n] = (f32x4){0.f, 0.f, 0.f, 0.f};

    auto stage = [&](int t, int bsel) {
        const int k0 = t << 5;
        #pragma unroll
        for (int i = 0; i < 2; ++i) {
            const int blk = i * 4 + wv;
            const int f   = blk * 64 + lane;
            const int r   = f >> 2;
            const int cbyte = (f & 3) << 4;
            const char* sa = (const char*)A  + (((size_t)(bm + r) * K + k0) << 1) + cbyte;
            const char* sb = (const char*)Wt + (((size_t)(bn + r) * K + k0) << 1) + cbyte;
            __builtin_amdgcn_global_load_lds((const void*)sa,
                (void*)((char*)(&As[bsel][0][0]) + blk * 1024), 16, 0, 0);
            __builtin_amdgcn_global_load_lds((const void*)sb,
                (void*)((char*)(&Bs[bsel][0][0]) + blk * 1024), 16, 0, 0);
        }
    };

    const int nt = K >> 5;
    stage(0, 0);
    __syncthreads();

    for (int t = 0; t < nt; ++t) {
        const int b = t & 1;
        if (t + 1 < nt) stage(t + 1, b ^ 1);
        bf16x8 af[4], bfr[4];
        #pragma unroll
        for (int m = 0; m < 4; ++m)
            af[m] = *(const bf16x8*)&As[b][wm + m * 16 + lr][lh * 8];
        #pragma unroll
        for (int n = 0; n < 4; ++n)
            bfr[n] = *(const bf16x8*)&Bs[b][wn + n * 16 + lr][lh * 8];
        #pragma unroll
        for (int m = 0; m < 4; ++m)
            #pragma unroll
            for (int n = 0; n < 4; ++n)
                acc[m][n] = __builtin_amdgcn_mfma_f32_16x16x32_bf16(
                    af[m], bfr[n], acc[m][n], 0, 0, 0);
        __syncthreads();
    }

    #pragma unroll
    for (int n = 0; n < 4; ++n) {
        const int col = bn + wn + n * 16 + lr;
        const float bcol = bias[col];
        #pragma unroll
        for (int m = 0; m < 4; ++m) {
            #pragma unroll
            for (int i = 0; i < 4; ++i) {
                const int row = bm + wm + m * 16 + lh * 4 + i;
                float v = acc[m][n][i] + bcol;
                if (RELU) v = fmaxf(v, 0.f);
                if (OUTF32) ((float*)C)[(size_t)row * N + col] = v;
                else        ((ushort*)C)[(size_t)row * N + col] = f2bf(v);
            }
        }
    }
}

// ---------------- prep bodies ----------------
__device__ __forceinline__ void wt_convert_dev(
    const float* __restrict__ W, ushort* __restrict__ Wt, int K, int N,
    int bx, int by, void* smem)
{
    ushort (*t)[65] = (ushort(*)[65])smem;
    const int kb = by << 6, nb = bx << 6;
    const int c  = threadIdx.x & 63;
    const int r0 = (threadIdx.x >> 6) << 4;
    #pragma unroll
    for (int i = 0; i < 16; ++i)
        t[r0 + i][c] = f2bf(W[(size_t)(kb + r0 + i) * N + nb + c]);
    __syncthreads();
    #pragma unroll
    for (int i = 0; i < 16; ++i)
        Wt[(size_t)(nb + r0 + i) * K + kb + c] = t[c][r0 + i];
}

__device__ __forceinline__ void prep_dispatch(
    int b,
    const float* dW1, const float* dW2, const float* dW3, const float* dW4,
    ushort* Wt1, ushort* Wt2, ushort* Wt3, ushort* Wt4,
    const float* cb, float* sq, float* cbt, void* smem)
{
    if (b < 64)  { wt_convert_dev(dW1, Wt1, 128,  2048, b % 32, b / 32, smem); return; }
    b -= 64;
    if (b < 512) { wt_convert_dev(dW2, Wt2, 2048, 1024, b % 16, b / 16, smem); return; }
    b -= 512;
    if (b < 128) { wt_convert_dev(dW3, Wt3, 1024, 512,  b % 8,  b / 8,  smem); return; }
    b -= 128;
    if (b < 96)  { wt_convert_dev(dW4, Wt4, 512,  768,  b % 12, b / 12, smem); return; }
    b -= 96;
    if (b < 4) {
        int k = b * 256 + threadIdx.x;
        const float* r = cb + ((size_t)k << 7);
        float s = 0.f;
        #pragma unroll 8
        for (int d = 0; d < 128; ++d) s = fmaf(r[d], r[d], s);
        sq[k] = s;
        return;
    }
    b -= 4;
    {
        float (*t)[65] = (float(*)[65])smem;
        const int kb = (b % 16) << 6;
        const int db = (b / 16) << 6;
        const int c  = threadIdx.x & 63;
        const int r0 = (threadIdx.x >> 6) << 4;
        #pragma unroll
        for (int i = 0; i < 16; ++i)
            t[r0 + i][c] = cb[(size_t)(kb + r0 + i) * 128 + db + c];
        __syncthreads();
        #pragma unroll
        for (int i = 0; i < 16; ++i)
            cbt[(size_t)(db + r0 + i) * 1024 + kb + c] = t[c][r0 + i];
    }
}

// ---- fused enc1 + prep (pool = 24832 B: wide-dbuf needs it) ----
__global__ __launch_bounds__(256) void enc1_prep(
    const float* A, const float* W, const float* b, float* C, int encb,
    const float* dW1, const float* dW2, const float* dW3, const float* dW4,
    ushort* Wt1, ushort* Wt2, ushort* Wt3, ushort* Wt4,
    const float* cb, float* sq, float* cbt)
{
    __shared__ __align__(16) char pool[24832];
    const int bid = blockIdx.x;
    if (bid < encb) {
        gemm_f32_wide_dev<true>(A, W, b, C, 768, 2048, bid & 7, bid >> 3, pool);
    } else {
        prep_dispatch(bid - encb, dW1, dW2, dW3, dW4, Wt1, Wt2, Wt3, Wt4,
                      cb, sq, cbt, pool);
    }
}

// ---- named wrappers ----
__global__ __launch_bounds__(256) void enc2_gemm(const float* A, const float* W, const float* b, float* C)
{ __shared__ __align__(16) char pool[24832];
  int bx, by; xcd_swz(bx, by);
  gemm_f32_wide_dev<true>(A, W, b, C, 2048, 1024, bx, by, pool); }
__global__ __launch_bounds__(256) void enc3_gemm(const float* A, const float* W, const float* b, float* C)
{ __shared__ __align__(16) char pool[24832];
  int bx, by; xcd_swz(bx, by);
  gemm_f32_wide_dev<true>(A, W, b, C, 1024, 512, bx, by, pool); }
__global__ __launch_bounds__(256) void enc4_gemm(const float* A, const float* W, const float* b, float* C)
{ int bx, by; xcd_swz(bx, by); gemm_f32_64_dev<false>(A, W, b, C, 512, 128, bx, by); }
__global__ __launch_bounds__(256) void dec1_gemm(const ushort* A, const ushort* Wt, const float* b, void* C)
{ int bx, by; xcd_swz(bx, by); gemm_bf16_dev<true, false>(A, Wt, b, C, 128, 2048, bx, by); }
__global__ __launch_bounds__(256) void dec2_gemm(const ushort* A, const ushort* Wt, const float* b, void* C)
{ int bx, by; xcd_swz(bx, by); gemm_bf16_dev<true, false>(A, Wt, b, C, 2048, 1024, bx, by); }
__global__ __launch_bounds__(256) void dec3_gemm(const ushort* A, const ushort* Wt, const float* b, void* C)
{ int bx, by; xcd_swz(bx, by); gemm_bf16_dev<true, false>(A, Wt, b, C, 1024, 512, bx, by); }
__global__ __launch_bounds__(256) void dec4_gemm(const ushort* A, const ushort* Wt, const float* b, void* C)
{ int bx, by; xcd_swz(bx, by); gemm_bf16_dev<false, true>(A, Wt, b, C, 512, 768, bx, by); }

// ---------------- fully-fused residual quantization (R9-proven) ----------
__global__ __launch_bounds__(256) void rq_all(
    const float* __restrict__ z, const float* __restrict__ cbt,
    const float* __restrict__ sq, const float* __restrict__ cb,
    ushort* __restrict__ ZHb, float* __restrict__ codes)
{
    __shared__ float As[128][68];
    __shared__ float Bs[32][132];
    __shared__ float sqs[1024];
    __shared__ float rrs[64];

    const int tid = threadIdx.x;
    const int bm  = blockIdx.x << 6;
    const int tr  = tid >> 4;
    const int c   = tid & 15;
    const int tn4 = c << 2;
    const int lb_row = tid >> 5;
    const int lb_col = (tid & 31) << 2;

    #pragma unroll
    for (int i = 0; i < 4; ++i) sqs[tid + (i << 8)] = sq[tid + (i << 8)];

    float zh[4][8];
    #pragma unroll
    for (int i = 0; i < 4; ++i) {
        const int r_  = (tr << 2) + i;
        const float* zp = z + (size_t)(bm + r_) * 128 + (c << 3);
        float4 z0 = *(const float4*)(zp);
        float4 z1 = *(const float4*)(zp + 4);
        #pragma unroll
        for (int j = 0; j < 8; ++j) zh[i][j] = 0.f;
        As[(c << 3) + 0][r_] = z0.x; As[(c << 3) + 1][r_] = z0.y;
        As[(c << 3) + 2][r_] = z0.z; As[(c << 3) + 3][r_] = z0.w;
        As[(c << 3) + 4][r_] = z1.x; As[(c << 3) + 5][r_] = z1.y;
        As[(c << 3) + 6][r_] = z1.z; As[(c << 3) + 7][r_] = z1.w;
        float p = z0.x * z0.x;
        p = fmaf(z0.y, z0.y, p); p = fmaf(z0.z, z0.z, p);
        p = fmaf(z0.w, z0.w, p); p = fmaf(z1.x, z1.x, p);
        p = fmaf(z1.y, z1.y, p); p = fmaf(z1.z, z1.z, p);
        p = fmaf(z1.w, z1.w, p);
        #pragma unroll
        for (int o = 8; o >= 1; o >>= 1) p += __shfl_xor(p, o);
        if (c == 0) rrs[r_] = p;
    }
    __syncthreads();

    for (int t = 0; t < 3; ++t) {
        float rr_[4];
        #pragma unroll
        for (int i = 0; i < 4; ++i) rr_[i] = rrs[(tr << 2) + i];

        float best_d[4] = {FLT_MAX_C, FLT_MAX_C, FLT_MAX_C, FLT_MAX_C};
        int   best_i[4] = {0, 0, 0, 0};

        for (int bx = 0; bx < 8; ++bx) {
            const int bn = bx << 7;
            const float* bptr = cbt + (size_t)lb_row * 1024 + bn + lb_col;
            float4 bv0 = *(const float4*)(bptr);
            float4 bv1 = *(const float4*)(bptr + (size_t)8  * 1024);
            float4 bv2 = *(const float4*)(bptr + (size_t)16 * 1024);
            float4 bv3 = *(const float4*)(bptr + (size_t)24 * 1024);

            float acc[4][8];
            #pragma unroll
            for (int i = 0; i < 4; ++i)
                #pragma unroll
                for (int j = 0; j < 8; ++j) acc[i][j] = 0.f;

            for (int k0 = 0; k0 < 128; k0 += 32) {
                __syncthreads();
                *(float4*)(&Bs[lb_row +  0][lb_col]) = bv0;
                *(float4*)(&Bs[lb_row +  8][lb_col]) = bv1;
                *(float4*)(&Bs[lb_row + 16][lb_col]) = bv2;
                *(float4*)(&Bs[lb_row + 24][lb_col]) = bv3;
                __syncthreads();
                if (k0 + 32 < 128) {
                    bv0 = *(const float4*)(bptr + (size_t)(k0 + 32) * 1024);
                    bv1 = *(const float4*)(bptr + (size_t)(k0 + 40) * 1024);
                    bv2 = *(const float4*)(bptr + (size_t)(k0 + 48) * 1024);
                    bv3 = *(const float4*)(bptr + (size_t)(k0 + 56) * 1024);
                }
                #pragma unroll
                for (int kk = 0; kk < 32; ++kk) {
                    float a[4], b[8];
                    *(float4*)(a)     = *(const float4*)(&As[k0 + kk][tr << 2]);
                    *(float4*)(b)     = *(const float4*)(&Bs[kk][tn4]);
                    *(float4*)(b + 4) = *(const float4*)(&Bs[kk][tn4 + 64]);
                    #pragma unroll
                    for (int i = 0; i < 4; ++i)
                        #pragma unroll
                        for (int j = 0; j < 8; ++j)
                            acc[i][j] = fmaf(a[i], b[j], acc[i][j]);
                }
            }
            #pragma unroll
            for (int i = 0; i < 4; ++i) {
                #pragma unroll
                for (int j = 0; j < 8; ++j) {
                    const int col = bn + tn4 + (j < 4 ? j : 60 + j);
                    float d = (rr_[i] + sqs[col]) - 2.f * acc[i][j];
                    if (d < best_d[i]) { best_d[i] = d; best_i[i] = col; }
                }
            }
        }

        #pragma unroll
        for (int i = 0; i < 4; ++i) {
            float bd = best_d[i]; int bi = best_i[i];
            #pragma unroll
            for (int o = 8; o >= 1; o >>= 1) {
                float od = __shfl_xor(bd, o);
                int   oi = __shfl_xor(bi, o);
                if (od < bd || (od == bd && oi < bi)) { bd = od; bi = oi; }
            }
            best_i[i] = bi;
        }

        __syncthreads();

        #pragma unroll
        for (int i = 0; i < 4; ++i) {
            const int r_  = (tr << 2) + i;
            const int row = bm + r_;
            if (c == 0) codes[(size_t)row * 3 + t] = (float)best_i[i];

            const float* cbp = cb + ((size_t)best_i[i] << 7) + (c << 3);
            float4 c0 = *(const float4*)(cbp);
            float4 c1 = *(const float4*)(cbp + 4);
            zh[i][0] += c0.x; zh[i][1] += c0.y;
            zh[i][2] += c0.z; zh[i][3] += c0.w;
            zh[i][4] += c1.x; zh[i][5] += c1.y;
            zh[i][6] += c1.z; zh[i][7] += c1.w;

            if (t < 2) {
                const float* zp = z + (size_t)row * 128 + (c << 3);
                float4 z0 = *(const float4*)(zp);
                float4 z1 = *(const float4*)(zp + 4);
                float r0 = z0.x - zh[i][0], r1 = z0.y - zh[i][1];
                float r2 = z0.z - zh[i][2], r3 = z0.w - zh[i][3];
                float r4 = z1.x - zh[i][4], r5 = z1.y - zh[i][5];
                float r6 = z1.z - zh[i][6], r7 = z1.w - zh[i][7];
                As[(c << 3) + 0][r_] = r0; As[(c << 3) + 1][r_] = r1;
                As[(c << 3) + 2][r_] = r2; As[(c << 3) + 3][r_] = r3;
                As[(c << 3) + 4][r_] = r4; As[(c << 3) + 5][r_] = r5;
                As[(c << 3) + 6][r_] = r6; As[(c << 3) + 7][r_] = r7;
                float p = r0 * r0;
                p = fmaf(r1, r1, p); p = fmaf(r2, r2, p);
                p = fmaf(r3, r3, p); p = fmaf(r4, r4, p);
                p = fmaf(r5, r5, p); p = fmaf(r6, r6, p);
                p = fmaf(r7, r7, p);
                #pragma unroll
                for (int o = 8; o >= 1; o >>= 1) p += __shfl_xor(p, o);
                if (c == 0) rrs[r_] = p;
            } else {
                ushort4 o0, o1;
                o0.x = f2bf(zh[i][0]); o0.y = f2bf(zh[i][1]);
                o0.z = f2bf(zh[i][2]); o0.w = f2bf(zh[i][3]);
                o1.x = f2bf(zh[i][4]); o1.y = f2bf(zh[i][5]);
                o1.z = f2bf(zh[i][6]); o1.w = f2bf(zh[i][7]);
                ushort* zbp = ZHb + (size_t)row * 128 + (c << 3);
                *(ushort4*)(zbp)     = o0;
                *(ushort4*)(zbp + 4) = o1;
            }
        }
        if (t < 2) __syncthreads();
    }
}

extern "C" void kernel_launch(void* const* d_in, const int* in_sizes, int n_in,
                              void* d_out, int out_size, void* d_ws, size_t ws_size,
                              hipStream_t stream)
{
    const float* x   = (const float*)d_in[0];
    const float* eW1 = (const float*)d_in[1];
    const float* eb1 = (const float*)d_in[2];
    const float* eW2 = (const float*)d_in[3];
    const float* eb2 = (const float*)d_in[4];
    const float* eW3 = (const float*)d_in[5];
    const float* eb3 = (const float*)d_in[6];
    const float* eW4 = (const float*)d_in[7];
    const float* eb4 = (const float*)d_in[8];
    const float* dW1 = (const float*)d_in[9];
    const float* db1 = (const float*)d_in[10];
    const float* dW2 = (const float*)d_in[11];
    const float* db2 = (const float*)d_in[12];
    const float* dW3 = (const float*)d_in[13];
    const float* db3 = (const float*)d_in[14];
    const float* dW4 = (const float*)d_in[15];
    const float* db4 = (const float*)d_in[16];
    const float* cb  = (const float*)d_in[17];

    float* out   = (float*)d_out;
    float* codes = out + (size_t)32768 * 768;

    ushort* Wt1 = (ushort*)d_ws;                       // 2048 x 128
    ushort* Wt2 = Wt1 + (size_t)2048 * 128;            // 1024 x 2048
    ushort* Wt3 = Wt2 + (size_t)1024 * 2048;           // 512 x 1024
    ushort* Wt4 = Wt3 + (size_t)512 * 1024;            // 768 x 512
    float*  sq  = (float*)(Wt4 + (size_t)768 * 512);   // 1024
    float*  cbt = sq + 1024;                           // 128 x 1024
    float*  act = cbt + (size_t)128 * 1024;
    const size_t fixed_b = (char*)act - (char*)d_ws;

    int mc = 32768;
    while (mc > 1024) {
        if (fixed_b + (size_t)mc * 15104 <= ws_size) break;
        mc >>= 1;
    }

    float*  R1  = act;                               // mc x 2048 f32
    float*  R2  = R1 + (size_t)mc * 2048;            // mc x 1024 f32
    float*  R3  = R2 + (size_t)mc * 1024;            // mc x 512  f32
    float*  RZ  = R3 + (size_t)mc * 512;             // mc x 128  f32 (z)
    ushort* ZHb = (ushort*)(RZ + (size_t)mc * 128);  // mc x 128 bf16
    ushort* D1  = (ushort*)R1;
    ushort* D2  = (ushort*)R2;
    ushort* D3  = (ushort*)R3;

    const int mg = mc >> 7;
    bool first = true;
    for (int r0 = 0; r0 < 32768; r0 += mc) {
        const float* xi     = x     + (size_t)r0 * 768;
        float*       outi   = out   + (size_t)r0 * 768;
        float*       codesi = codes + (size_t)r0 * 3;
        const int encb = 8 * mg;
        const int prepb = first ? 836 : 0;
        enc1_prep<<<encb + prepb, 256, 0, stream>>>(
            xi, eW1, eb1, R1, encb,
            dW1, dW2, dW3, dW4, Wt1, Wt2, Wt3, Wt4, cb, sq, cbt);
        first = false;
        enc2_gemm<<<dim3( 4, mg), 256, 0, stream>>>(R1, eW2, eb2, R2);
        enc3_gemm<<<dim3( 2, mg), 256, 0, stream>>>(R2, eW3, eb3, R3);
        enc4_gemm<<<dim3( 1, mc >> 6), 256, 0, stream>>>(R3, eW4, eb4, RZ);
        rq_all<<<mc >> 6, 256, 0, stream>>>(RZ, cbt, sq, cb, ZHb, codesi);
        dec1_gemm<<<dim3(16, mg), 256, 0, stream>>>(ZHb, Wt1, db1, D1);
        dec2_gemm<<<dim3( 8, mg), 256, 0, stream>>>(D1,  Wt2, db2, D2);
        dec3_gemm<<<dim3( 4, mg), 256, 0, stream>>>(D2,  Wt3, db3, D3);
        dec4_gemm<<<dim3( 6, mg), 256, 0, stream>>>(D3,  Wt4, db4, outi);
    }
}

// Round 18
// 3757.678 us; speedup vs baseline: 1.3534x; 1.3534x over previous
//
#include <hip/hip_runtime.h>

#define FLT_MAX_C 3.402823466e+38f

typedef __attribute__((ext_vector_type(8))) __bf16 bf16x8;
typedef __attribute__((ext_vector_type(4))) float f32x4;

static __device__ __forceinline__ ushort f2bf(float x) {
    union { float f; unsigned u; } v; v.f = x;
    unsigned r = (v.u + 0x7FFFu + ((v.u >> 16) & 1u)) >> 16;
    return (ushort)r;
}

// bijective XCD swizzle (m204)
static __device__ __forceinline__ void xcd_swz(int& bx, int& by) {
    const int gx = gridDim.x;
    const int nwg = gx * gridDim.y;
    const int bid = blockIdx.y * gx + blockIdx.x;
    const int q = nwg >> 3, r = nwg & 7;
    const int xcd = bid & 7, lid = bid >> 3;
    const int swz = (xcd < r ? xcd * (q + 1) : r * (q + 1) + (xcd - r) * q) + lid;
    bx = swz % gx;
    by = swz / gx;
}

// ======== fp32 GEMM wide body: 128x256 tile, 8x16 microtile, BK=8 ========
// Single-buffered, 2 barriers/K-step, prefetch between barriers. Proven
// R13/R15 structure: VGPR=128, enc2 @ 775us / VALUBusy 73%.
template<bool RELU>
__device__ __forceinline__ void gemm_f32_wide_dev(
    const float* __restrict__ A, const float* __restrict__ W,
    const float* __restrict__ bias, float* __restrict__ C, int K, int N,
    int bxi, int byi, void* smem)
{
    float (*As)[128] = (float(*)[128])smem;                    // 4096 B
    float (*Bs)[260] = (float(*)[260])((char*)smem + 4096);    // 8320 B
    const int tid = threadIdx.x;
    const int bm = byi << 7;
    const int bn = bxi << 8;

    const int la_row = tid >> 1;
    const int la_k   = (tid & 1) << 2;
    const int tm4 = (tid >> 4) << 2;
    const int tn4 = (tid & 15) << 2;
    const int bf_row  = tid >> 6;
    const int bf_col4 = (tid & 63) << 2;

    float acc[8][16];
    #pragma unroll
    for (int i = 0; i < 8; ++i)
        #pragma unroll
        for (int j = 0; j < 16; ++j) acc[i][j] = 0.f;

    const float* aptr = A + (size_t)(bm + la_row) * K + la_k;
    const float* bptr = W + (size_t)bf_row * N + bn + bf_col4;

    float4 av = *(const float4*)(aptr);
    float4 bv0 = *(const float4*)(bptr);
    float4 bv1 = *(const float4*)(bptr + (size_t)4 * N);

    for (int k0 = 0; k0 < K; k0 += 8) {
        __syncthreads();
        As[la_k + 0][la_row] = av.x;
        As[la_k + 1][la_row] = av.y;
        As[la_k + 2][la_row] = av.z;
        As[la_k + 3][la_row] = av.w;
        *(float4*)(&Bs[bf_row][bf_col4])     = bv0;
        *(float4*)(&Bs[bf_row + 4][bf_col4]) = bv1;
        __syncthreads();
        if (k0 + 8 < K) {
            av  = *(const float4*)(aptr + k0 + 8);
            bv0 = *(const float4*)(bptr + (size_t)(k0 + 8) * N);
            bv1 = *(const float4*)(bptr + (size_t)(k0 + 12) * N);
        }
        #pragma unroll
        for (int kk = 0; kk < 8; ++kk) {
            float a[8], bfr[16];
            *(float4*)(a)      = *(const float4*)(&As[kk][tm4]);
            *(float4*)(a + 4)  = *(const float4*)(&As[kk][tm4 + 64]);
            #pragma unroll
            for (int q = 0; q < 4; ++q)
                *(float4*)(bfr + q * 4) = *(const float4*)(&Bs[kk][tn4 + 64 * q]);
            #pragma unroll
            for (int i = 0; i < 8; ++i)
                #pragma unroll
                for (int j = 0; j < 16; ++j)
                    acc[i][j] = fmaf(a[i], bfr[j], acc[i][j]);
        }
    }

    float bb[16];
    #pragma unroll
    for (int q = 0; q < 4; ++q)
        #pragma unroll
        for (int jj = 0; jj < 4; ++jj)
            bb[q * 4 + jj] = bias[bn + tn4 + 64 * q + jj];

    #pragma unroll
    for (int i = 0; i < 8; ++i) {
        int row = bm + tm4 + (i < 4 ? i : 60 + i);
        float* cp = C + (size_t)row * N + bn + tn4;
        #pragma unroll
        for (int q = 0; q < 4; ++q) {
            float4 v;
            v.x = acc[i][q * 4 + 0] + bb[q * 4 + 0];
            v.y = acc[i][q * 4 + 1] + bb[q * 4 + 1];
            v.z = acc[i][q * 4 + 2] + bb[q * 4 + 2];
            v.w = acc[i][q * 4 + 3] + bb[q * 4 + 3];
            if (RELU) {
                v.x = fmaxf(v.x, 0.f); v.y = fmaxf(v.y, 0.f);
                v.z = fmaxf(v.z, 0.f); v.w = fmaxf(v.w, 0.f);
            }
            *(float4*)(cp + 64 * q) = v;
        }
    }
}

// ========== fp32 GEMM small-M body (BM=64, BN=128, BK=16) for enc4 ==========
template<bool RELU>
__device__ __forceinline__ void gemm_f32_64_dev(
    const float* __restrict__ A, const float* __restrict__ W,
    const float* __restrict__ bias, float* __restrict__ C, int K, int N,
    int bxi, int byi)
{
    __shared__ float As[16][64];
    __shared__ float Bs[16][132];
    const int tid = threadIdx.x;
    const int bm = byi << 6;
    const int bn = bxi << 7;

    const int la_row = tid & 63;
    const int la_k   = (tid >> 6) << 2;
    const int lb_row = tid >> 5;
    const int lb_col = (tid & 31) << 2;
    const int tr = tid >> 4;
    const int tc = tid & 15;

    float acc[4][8];
    #pragma unroll
    for (int i = 0; i < 4; ++i)
        #pragma unroll
        for (int j = 0; j < 8; ++j) acc[i][j] = 0.f;

    const float* aptr = A + (size_t)(bm + la_row) * K + la_k;
    const float* bptr = W + (size_t)lb_row * N + bn + lb_col;

    float4 av = *(const float4*)(aptr);
    float4 bv0 = *(const float4*)(bptr);
    float4 bv1 = *(const float4*)(bptr + (size_t)8 * N);

    for (int k0 = 0; k0 < K; k0 += 16) {
        __syncthreads();
        As[la_k + 0][la_row] = av.x;
        As[la_k + 1][la_row] = av.y;
        As[la_k + 2][la_row] = av.z;
        As[la_k + 3][la_row] = av.w;
        *(float4*)(&Bs[lb_row][lb_col]) = bv0;
        *(float4*)(&Bs[lb_row + 8][lb_col]) = bv1;
        __syncthreads();
        if (k0 + 16 < K) {
            av  = *(const float4*)(aptr + k0 + 16);
            bv0 = *(const float4*)(bptr + (size_t)(k0 + 16) * N);
            bv1 = *(const float4*)(bptr + (size_t)(k0 + 24) * N);
        }
        #pragma unroll
        for (int kk = 0; kk < 16; ++kk) {
            float a[4], b[8];
            *(float4*)(a) = *(const float4*)(&As[kk][tr << 2]);
            *(float4*)(b)     = *(const float4*)(&Bs[kk][tc << 2]);
            *(float4*)(b + 4) = *(const float4*)(&Bs[kk][(tc << 2) + 64]);
            #pragma unroll
            for (int i = 0; i < 4; ++i)
                #pragma unroll
                for (int j = 0; j < 8; ++j)
                    acc[i][j] = fmaf(a[i], b[j], acc[i][j]);
        }
    }

    float bb[8];
    #pragma unroll
    for (int j = 0; j < 8; ++j)
        bb[j] = bias[bn + (tc << 2) + (j < 4 ? j : 60 + j)];

    #pragma unroll
    for (int i = 0; i < 4; ++i) {
        float* cp = C + (size_t)(bm + (tr << 2) + i) * N + bn + (tc << 2);
        float4 v0, v1;
        v0.x = acc[i][0] + bb[0]; v0.y = acc[i][1] + bb[1];
        v0.z = acc[i][2] + bb[2]; v0.w = acc[i][3] + bb[3];
        v1.x = acc[i][4] + bb[4]; v1.y = acc[i][5] + bb[5];
        v1.z = acc[i][6] + bb[6]; v1.w = acc[i][7] + bb[7];
        if (RELU) {
            v0.x = fmaxf(v0.x, 0.f); v0.y = fmaxf(v0.y, 0.f);
            v0.z = fmaxf(v0.z, 0.f); v0.w = fmaxf(v0.w, 0.f);
            v1.x = fmaxf(v1.x, 0.f); v1.y = fmaxf(v1.y, 0.f);
            v1.z = fmaxf(v1.z, 0.f); v1.w = fmaxf(v1.w, 0.f);
        }
        *(float4*)(cp) = v0;
        *(float4*)(cp + 64) = v1;
    }
}

// ====== bf16 MFMA GEMM (decoder): K_STEP=32, 2-phase double-buffer ======
template<bool RELU, bool OUTF32>
__device__ __forceinline__ void gemm_bf16_dev(
    const ushort* __restrict__ A, const ushort* __restrict__ Wt,
    const float* __restrict__ bias, void* __restrict__ C, int K, int N,
    int bxi, int byi)
{
    __shared__ __align__(16) ushort As[2][128][32];
    __shared__ __align__(16) ushort Bs[2][128][32];
    const int tid  = threadIdx.x;
    const int lane = tid & 63;
    const int wv   = tid >> 6;
    const int wm   = (wv >> 1) << 6;
    const int wn   = (wv & 1) << 6;
    const int bm   = byi << 7;
    const int bn   = bxi << 7;
    const int lr   = lane & 15;
    const int lh   = lane >> 4;

    f32x4 acc[4][4];
    #pragma unroll
    for (int m = 0; m < 4; ++m)
        #pragma unroll
        for (int n = 0; n < 4; ++n) acc[m][n] = (f32x4){0.f, 0.f, 0.f, 0.f};

    auto stage = [&](int t, int bsel) {
        const int k0 = t << 5;
        #pragma unroll
        for (int i = 0; i < 2; ++i) {
            const int blk = i * 4 + wv;
            const int f   = blk * 64 + lane;
            const int r   = f >> 2;
            const int cbyte = (f & 3) << 4;
            const char* sa = (const char*)A  + (((size_t)(bm + r) * K + k0) << 1) + cbyte;
            const char* sb = (const char*)Wt + (((size_t)(bn + r) * K + k0) << 1) + cbyte;
            __builtin_amdgcn_global_load_lds((const void*)sa,
                (void*)((char*)(&As[bsel][0][0]) + blk * 1024), 16, 0, 0);
            __builtin_amdgcn_global_load_lds((const void*)sb,
                (void*)((char*)(&Bs[bsel][0][0]) + blk * 1024), 16, 0, 0);
        }
    };

    const int nt = K >> 5;
    stage(0, 0);
    __syncthreads();

    for (int t = 0; t < nt; ++t) {
        const int b = t & 1;
        if (t + 1 < nt) stage(t + 1, b ^ 1);
        bf16x8 af[4], bfr[4];
        #pragma unroll
        for (int m = 0; m < 4; ++m)
            af[m] = *(const bf16x8*)&As[b][wm + m * 16 + lr][lh * 8];
        #pragma unroll
        for (int n = 0; n < 4; ++n)
            bfr[n] = *(const bf16x8*)&Bs[b][wn + n * 16 + lr][lh * 8];
        #pragma unroll
        for (int m = 0; m < 4; ++m)
            #pragma unroll
            for (int n = 0; n < 4; ++n)
                acc[m][n] = __builtin_amdgcn_mfma_f32_16x16x32_bf16(
                    af[m], bfr[n], acc[m][n], 0, 0, 0);
        __syncthreads();
    }

    #pragma unroll
    for (int n = 0; n < 4; ++n) {
        const int col = bn + wn + n * 16 + lr;
        const float bcol = bias[col];
        #pragma unroll
        for (int m = 0; m < 4; ++m) {
            #pragma unroll
            for (int i = 0; i < 4; ++i) {
                const int row = bm + wm + m * 16 + lh * 4 + i;
                float v = acc[m][n][i] + bcol;
                if (RELU) v = fmaxf(v, 0.f);
                if (OUTF32) ((float*)C)[(size_t)row * N + col] = v;
                else        ((ushort*)C)[(size_t)row * N + col] = f2bf(v);
            }
        }
    }
}

// ---------------- prep bodies ----------------
__device__ __forceinline__ void wt_convert_dev(
    const float* __restrict__ W, ushort* __restrict__ Wt, int K, int N,
    int bx, int by, void* smem)
{
    ushort (*t)[65] = (ushort(*)[65])smem;
    const int kb = by << 6, nb = bx << 6;
    const int c  = threadIdx.x & 63;
    const int r0 = (threadIdx.x >> 6) << 4;
    #pragma unroll
    for (int i = 0; i < 16; ++i)
        t[r0 + i][c] = f2bf(W[(size_t)(kb + r0 + i) * N + nb + c]);
    __syncthreads();
    #pragma unroll
    for (int i = 0; i < 16; ++i)
        Wt[(size_t)(nb + r0 + i) * K + kb + c] = t[c][r0 + i];
}

__device__ __forceinline__ void prep_dispatch(
    int b,
    const float* dW1, const float* dW2, const float* dW3, const float* dW4,
    ushort* Wt1, ushort* Wt2, ushort* Wt3, ushort* Wt4,
    const float* cb, float* sq, float* cbt, void* smem)
{
    if (b < 64)  { wt_convert_dev(dW1, Wt1, 128,  2048, b % 32, b / 32, smem); return; }
    b -= 64;
    if (b < 512) { wt_convert_dev(dW2, Wt2, 2048, 1024, b % 16, b / 16, smem); return; }
    b -= 512;
    if (b < 128) { wt_convert_dev(dW3, Wt3, 1024, 512,  b % 8,  b / 8,  smem); return; }
    b -= 128;
    if (b < 96)  { wt_convert_dev(dW4, Wt4, 512,  768,  b % 12, b / 12, smem); return; }
    b -= 96;
    if (b < 4) {
        int k = b * 256 + threadIdx.x;
        const float* r = cb + ((size_t)k << 7);
        float s = 0.f;
        #pragma unroll 8
        for (int d = 0; d < 128; ++d) s = fmaf(r[d], r[d], s);
        sq[k] = s;
        return;
    }
    b -= 4;
    {
        float (*t)[65] = (float(*)[65])smem;
        const int kb = (b % 16) << 6;
        const int db = (b / 16) << 6;
        const int c  = threadIdx.x & 63;
        const int r0 = (threadIdx.x >> 6) << 4;
        #pragma unroll
        for (int i = 0; i < 16; ++i)
            t[r0 + i][c] = cb[(size_t)(kb + r0 + i) * 128 + db + c];
        __syncthreads();
        #pragma unroll
        for (int i = 0; i < 16; ++i)
            cbt[(size_t)(db + r0 + i) * 1024 + kb + c] = t[c][r0 + i];
    }
}

// ---- fused enc1 + prep ----
__global__ __launch_bounds__(256) void enc1_prep(
    const float* A, const float* W, const float* b, float* C, int encb,
    const float* dW1, const float* dW2, const float* dW3, const float* dW4,
    ushort* Wt1, ushort* Wt2, ushort* Wt3, ushort* Wt4,
    const float* cb, float* sq, float* cbt)
{
    __shared__ __align__(16) char pool[16640];
    const int bid = blockIdx.x;
    if (bid < encb) {
        gemm_f32_wide_dev<true>(A, W, b, C, 768, 2048, bid & 7, bid >> 3, pool);
    } else {
        prep_dispatch(bid - encb, dW1, dW2, dW3, dW4, Wt1, Wt2, Wt3, Wt4,
                      cb, sq, cbt, pool);
    }
}

// ---- named wrappers ----
__global__ __launch_bounds__(256) void enc2_gemm(const float* A, const float* W, const float* b, float* C)
{ __shared__ __align__(16) char pool[12416];
  int bx, by; xcd_swz(bx, by);
  gemm_f32_wide_dev<true>(A, W, b, C, 2048, 1024, bx, by, pool); }
__global__ __launch_bounds__(256) void enc3_gemm(const float* A, const float* W, const float* b, float* C)
{ __shared__ __align__(16) char pool[12416];
  int bx, by; xcd_swz(bx, by);
  gemm_f32_wide_dev<true>(A, W, b, C, 1024, 512, bx, by, pool); }
__global__ __launch_bounds__(256) void enc4_gemm(const float* A, const float* W, const float* b, float* C)
{ int bx, by; xcd_swz(bx, by); gemm_f32_64_dev<false>(A, W, b, C, 512, 128, bx, by); }
__global__ __launch_bounds__(256) void dec1_gemm(const ushort* A, const ushort* Wt, const float* b, void* C)
{ int bx, by; xcd_swz(bx, by); gemm_bf16_dev<true, false>(A, Wt, b, C, 128, 2048, bx, by); }
__global__ __launch_bounds__(256) void dec2_gemm(const ushort* A, const ushort* Wt, const float* b, void* C)
{ int bx, by; xcd_swz(bx, by); gemm_bf16_dev<true, false>(A, Wt, b, C, 2048, 1024, bx, by); }
__global__ __launch_bounds__(256) void dec3_gemm(const ushort* A, const ushort* Wt, const float* b, void* C)
{ int bx, by; xcd_swz(bx, by); gemm_bf16_dev<true, false>(A, Wt, b, C, 1024, 512, bx, by); }
__global__ __launch_bounds__(256) void dec4_gemm(const ushort* A, const ushort* Wt, const float* b, void* C)
{ int bx, by; xcd_swz(bx, by); gemm_bf16_dev<false, true>(A, Wt, b, C, 512, 768, bx, by); }

// ---------------- fully-fused residual quantization (R9-proven) ----------
__global__ __launch_bounds__(256) void rq_all(
    const float* __restrict__ z, const float* __restrict__ cbt,
    const float* __restrict__ sq, const float* __restrict__ cb,
    ushort* __restrict__ ZHb, float* __restrict__ codes)
{
    __shared__ float As[128][68];
    __shared__ float Bs[32][132];
    __shared__ float sqs[1024];
    __shared__ float rrs[64];

    const int tid = threadIdx.x;
    const int bm  = blockIdx.x << 6;
    const int tr  = tid >> 4;
    const int c   = tid & 15;
    const int tn4 = c << 2;
    const int lb_row = tid >> 5;
    const int lb_col = (tid & 31) << 2;

    #pragma unroll
    for (int i = 0; i < 4; ++i) sqs[tid + (i << 8)] = sq[tid + (i << 8)];

    float zh[4][8];
    #pragma unroll
    for (int i = 0; i < 4; ++i) {
        const int r_  = (tr << 2) + i;
        const float* zp = z + (size_t)(bm + r_) * 128 + (c << 3);
        float4 z0 = *(const float4*)(zp);
        float4 z1 = *(const float4*)(zp + 4);
        #pragma unroll
        for (int j = 0; j < 8; ++j) zh[i][j] = 0.f;
        As[(c << 3) + 0][r_] = z0.x; As[(c << 3) + 1][r_] = z0.y;
        As[(c << 3) + 2][r_] = z0.z; As[(c << 3) + 3][r_] = z0.w;
        As[(c << 3) + 4][r_] = z1.x; As[(c << 3) + 5][r_] = z1.y;
        As[(c << 3) + 6][r_] = z1.z; As[(c << 3) + 7][r_] = z1.w;
        float p = z0.x * z0.x;
        p = fmaf(z0.y, z0.y, p); p = fmaf(z0.z, z0.z, p);
        p = fmaf(z0.w, z0.w, p); p = fmaf(z1.x, z1.x, p);
        p = fmaf(z1.y, z1.y, p); p = fmaf(z1.z, z1.z, p);
        p = fmaf(z1.w, z1.w, p);
        #pragma unroll
        for (int o = 8; o >= 1; o >>= 1) p += __shfl_xor(p, o);
        if (c == 0) rrs[r_] = p;
    }
    __syncthreads();

    for (int t = 0; t < 3; ++t) {
        float rr_[4];
        #pragma unroll
        for (int i = 0; i < 4; ++i) rr_[i] = rrs[(tr << 2) + i];

        float best_d[4] = {FLT_MAX_C, FLT_MAX_C, FLT_MAX_C, FLT_MAX_C};
        int   best_i[4] = {0, 0, 0, 0};

        for (int bx = 0; bx < 8; ++bx) {
            const int bn = bx << 7;
            const float* bptr = cbt + (size_t)lb_row * 1024 + bn + lb_col;
            float4 bv0 = *(const float4*)(bptr);
            float4 bv1 = *(const float4*)(bptr + (size_t)8  * 1024);
            float4 bv2 = *(const float4*)(bptr + (size_t)16 * 1024);
            float4 bv3 = *(const float4*)(bptr + (size_t)24 * 1024);

            float acc[4][8];
            #pragma unroll
            for (int i = 0; i < 4; ++i)
                #pragma unroll
                for (int j = 0; j < 8; ++j) acc[i][j] = 0.f;

            for (int k0 = 0; k0 < 128; k0 += 32) {
                __syncthreads();
                *(float4*)(&Bs[lb_row +  0][lb_col]) = bv0;
                *(float4*)(&Bs[lb_row +  8][lb_col]) = bv1;
                *(float4*)(&Bs[lb_row + 16][lb_col]) = bv2;
                *(float4*)(&Bs[lb_row + 24][lb_col]) = bv3;
                __syncthreads();
                if (k0 + 32 < 128) {
                    bv0 = *(const float4*)(bptr + (size_t)(k0 + 32) * 1024);
                    bv1 = *(const float4*)(bptr + (size_t)(k0 + 40) * 1024);
                    bv2 = *(const float4*)(bptr + (size_t)(k0 + 48) * 1024);
                    bv3 = *(const float4*)(bptr + (size_t)(k0 + 56) * 1024);
                }
                #pragma unroll
                for (int kk = 0; kk < 32; ++kk) {
                    float a[4], b[8];
                    *(float4*)(a)     = *(const float4*)(&As[k0 + kk][tr << 2]);
                    *(float4*)(b)     = *(const float4*)(&Bs[kk][tn4]);
                    *(float4*)(b + 4) = *(const float4*)(&Bs[kk][tn4 + 64]);
                    #pragma unroll
                    for (int i = 0; i < 4; ++i)
                        #pragma unroll
                        for (int j = 0; j < 8; ++j)
                            acc[i][j] = fmaf(a[i], b[j], acc[i][j]);
                }
            }
            #pragma unroll
            for (int i = 0; i < 4; ++i) {
                #pragma unroll
                for (int j = 0; j < 8; ++j) {
                    const int col = bn + tn4 + (j < 4 ? j : 60 + j);
                    float d = (rr_[i] + sqs[col]) - 2.f * acc[i][j];
                    if (d < best_d[i]) { best_d[i] = d; best_i[i] = col; }
                }
            }
        }

        #pragma unroll
        for (int i = 0; i < 4; ++i) {
            float bd = best_d[i]; int bi = best_i[i];
            #pragma unroll
            for (int o = 8; o >= 1; o >>= 1) {
                float od = __shfl_xor(bd, o);
                int   oi = __shfl_xor(bi, o);
                if (od < bd || (od == bd && oi < bi)) { bd = od; bi = oi; }
            }
            best_i[i] = bi;
        }

        __syncthreads();

        #pragma unroll
        for (int i = 0; i < 4; ++i) {
            const int r_  = (tr << 2) + i;
            const int row = bm + r_;
            if (c == 0) codes[(size_t)row * 3 + t] = (float)best_i[i];

            const float* cbp = cb + ((size_t)best_i[i] << 7) + (c << 3);
            float4 c0 = *(const float4*)(cbp);
            float4 c1 = *(const float4*)(cbp + 4);
            zh[i][0] += c0.x; zh[i][1] += c0.y;
            zh[i][2] += c0.z; zh[i][3] += c0.w;
            zh[i][4] += c1.x; zh[i][5] += c1.y;
            zh[i][6] += c1.z; zh[i][7] += c1.w;

            if (t < 2) {
                const float* zp = z + (size_t)row * 128 + (c << 3);
                float4 z0 = *(const float4*)(zp);
                float4 z1 = *(const float4*)(zp + 4);
                float r0 = z0.x - zh[i][0], r1 = z0.y - zh[i][1];
                float r2 = z0.z - zh[i][2], r3 = z0.w - zh[i][3];
                float r4 = z1.x - zh[i][4], r5 = z1.y - zh[i][5];
                float r6 = z1.z - zh[i][6], r7 = z1.w - zh[i][7];
                As[(c << 3) + 0][r_] = r0; As[(c << 3) + 1][r_] = r1;
                As[(c << 3) + 2][r_] = r2; As[(c << 3) + 3][r_] = r3;
                As[(c << 3) + 4][r_] = r4; As[(c << 3) + 5][r_] = r5;
                As[(c << 3) + 6][r_] = r6; As[(c << 3) + 7][r_] = r7;
                float p = r0 * r0;
                p = fmaf(r1, r1, p); p = fmaf(r2, r2, p);
                p = fmaf(r3, r3, p); p = fmaf(r4, r4, p);
                p = fmaf(r5, r5, p); p = fmaf(r6, r6, p);
                p = fmaf(r7, r7, p);
                #pragma unroll
                for (int o = 8; o >= 1; o >>= 1) p += __shfl_xor(p, o);
                if (c == 0) rrs[r_] = p;
            } else {
                ushort4 o0, o1;
                o0.x = f2bf(zh[i][0]); o0.y = f2bf(zh[i][1]);
                o0.z = f2bf(zh[i][2]); o0.w = f2bf(zh[i][3]);
                o1.x = f2bf(zh[i][4]); o1.y = f2bf(zh[i][5]);
                o1.z = f2bf(zh[i][6]); o1.w = f2bf(zh[i][7]);
                ushort* zbp = ZHb + (size_t)row * 128 + (c << 3);
                *(ushort4*)(zbp)     = o0;
                *(ushort4*)(zbp + 4) = o1;
            }
        }
        if (t < 2) __syncthreads();
    }
}

extern "C" void kernel_launch(void* const* d_in, const int* in_sizes, int n_in,
                              void* d_out, int out_size, void* d_ws, size_t ws_size,
                              hipStream_t stream)
{
    const float* x   = (const float*)d_in[0];
    const float* eW1 = (const float*)d_in[1];
    const float* eb1 = (const float*)d_in[2];
    const float* eW2 = (const float*)d_in[3];
    const float* eb2 = (const float*)d_in[4];
    const float* eW3 = (const float*)d_in[5];
    const float* eb3 = (const float*)d_in[6];
    const float* eW4 = (const float*)d_in[7];
    const float* eb4 = (const float*)d_in[8];
    const float* dW1 = (const float*)d_in[9];
    const float* db1 = (const float*)d_in[10];
    const float* dW2 = (const float*)d_in[11];
    const float* db2 = (const float*)d_in[12];
    const float* dW3 = (const float*)d_in[13];
    const float* db3 = (const float*)d_in[14];
    const float* dW4 = (const float*)d_in[15];
    const float* db4 = (const float*)d_in[16];
    const float* cb  = (const float*)d_in[17];

    float* out   = (float*)d_out;
    float* codes = out + (size_t)32768 * 768;

    ushort* Wt1 = (ushort*)d_ws;                       // 2048 x 128
    ushort* Wt2 = Wt1 + (size_t)2048 * 128;            // 1024 x 2048
    ushort* Wt3 = Wt2 + (size_t)1024 * 2048;           // 512 x 1024
    ushort* Wt4 = Wt3 + (size_t)512 * 1024;            // 768 x 512
    float*  sq  = (float*)(Wt4 + (size_t)768 * 512);   // 1024
    float*  cbt = sq + 1024;                           // 128 x 1024
    float*  act = cbt + (size_t)128 * 1024;
    const size_t fixed_b = (char*)act - (char*)d_ws;

    int mc = 32768;
    while (mc > 1024) {
        if (fixed_b + (size_t)mc * 15104 <= ws_size) break;
        mc >>= 1;
    }

    float*  R1  = act;                               // mc x 2048 f32
    float*  R2  = R1 + (size_t)mc * 2048;            // mc x 1024 f32
    float*  R3  = R2 + (size_t)mc * 1024;            // mc x 512  f32
    float*  RZ  = R3 + (size_t)mc * 512;             // mc x 128  f32 (z)
    ushort* ZHb = (ushort*)(RZ + (size_t)mc * 128);  // mc x 128 bf16
    ushort* D1  = (ushort*)R1;
    ushort* D2  = (ushort*)R2;
    ushort* D3  = (ushort*)R3;

    const int mg = mc >> 7;
    bool first = true;
    for (int r0 = 0; r0 < 32768; r0 += mc) {
        const float* xi     = x     + (size_t)r0 * 768;
        float*       outi   = out   + (size_t)r0 * 768;
        float*       codesi = codes + (size_t)r0 * 3;
        const int encb = 8 * mg;
        const int prepb = first ? 836 : 0;
        enc1_prep<<<encb + prepb, 256, 0, stream>>>(
            xi, eW1, eb1, R1, encb,
            dW1, dW2, dW3, dW4, Wt1, Wt2, Wt3, Wt4, cb, sq, cbt);
        first = false;
        enc2_gemm<<<dim3( 4, mg), 256, 0, stream>>>(R1, eW2, eb2, R2);
        enc3_gemm<<<dim3( 2, mg), 256, 0, stream>>>(R2, eW3, eb3, R3);
        enc4_gemm<<<dim3( 1, mc >> 6), 256, 0, stream>>>(R3, eW4, eb4, RZ);
        rq_all<<<mc >> 6, 256, 0, stream>>>(RZ, cbt, sq, cb, ZHb, codesi);
        dec1_gemm<<<dim3(16, mg), 256, 0, stream>>>(ZHb, Wt1, db1, D1);
        dec2_gemm<<<dim3( 8, mg), 256, 0, stream>>>(D1,  Wt2, db2, D2);
        dec3_gemm<<<dim3( 4, mg), 256, 0, stream>>>(D2,  Wt3, db3, D3);
        dec4_gemm<<<dim3( 6, mg), 256, 0, stream>>>(D3,  Wt4, db4, outi);
    }
}